// Round 1
// baseline (314.244 us; speedup 1.0000x reference)
//
#include <hip/hip_runtime.h>

// Masked cumulative sum along dim=1.
//   x:    (256, 131072) float32
//   mask: (256, 131072) int32 (0/1)  [harness stages integer-like inputs as int32]
//   out:  (256, 131072) float32, out[b, j] = sum_{i<=j} (mask[b,i] ? x[b,i] : 0)
//
// Strategy: 1 block per row (256 blocks = 1/CU), 1024 threads (16 waves),
// row walked in 32 tiles of 4096 elements (float4 per thread).
// Per tile: thread scan(4) -> wave shfl scan(64) -> block combine via 16
// wave-sums in LDS (double-buffered so only ONE __syncthreads per tile) ->
// serial carry across tiles. Next tile's loads are prefetched before the
// current tile's barrier to hide HBM latency under the scan chain.

#define N_ROWS   256
#define N_COLS   131072
#define BLOCK    1024
#define VEC      4
#define TILE     (BLOCK * VEC)      // 4096
#define NTILES   (N_COLS / TILE)    // 32
#define NWAVES   (BLOCK / 64)       // 16

__global__ __launch_bounds__(BLOCK)
void masked_cumsum_kernel(const float* __restrict__ x,
                          const int* __restrict__ mask,
                          float* __restrict__ out) {
    __shared__ float waveSums[2][NWAVES];

    const int row  = blockIdx.x;
    const int tid  = threadIdx.x;
    const int lane = tid & 63;
    const int wave = tid >> 6;

    const size_t rowBase = (size_t)row * N_COLS;
    const float4* __restrict__ x4 = (const float4*)(x + rowBase);
    const int4*   __restrict__ m4 = (const int4*)(mask + rowBase);
    float4*       __restrict__ o4 = (float4*)(out + rowBase);

    float carry = 0.0f;

    // Prefetch tile 0.
    float4 xv = x4[tid];
    int4   mv = m4[tid];

    for (int t = 0; t < NTILES; ++t) {
        const float4 cx = xv;
        const int4   cm = mv;

        // Issue next tile's loads early (independent of this tile's math).
        if (t + 1 < NTILES) {
            const int nidx = (t + 1) * BLOCK + tid;
            xv = x4[nidx];
            mv = m4[nidx];
        }

        // Masked values + thread-local inclusive scan of 4.
        const float v0 = cm.x ? cx.x : 0.0f;
        const float v1 = cm.y ? cx.y : 0.0f;
        const float v2 = cm.z ? cx.z : 0.0f;
        const float v3 = cm.w ? cx.w : 0.0f;
        const float s0 = v0;
        const float s1 = s0 + v1;
        const float s2 = s1 + v2;
        const float s3 = s2 + v3;
        const float tsum = s3;

        // Wave-level inclusive scan over 64 lanes.
        float incl = tsum;
        #pragma unroll
        for (int d = 1; d < 64; d <<= 1) {
            const float y = __shfl_up(incl, d, 64);
            if (lane >= d) incl += y;
        }
        const float waveExcl = incl - tsum;

        if (lane == 63) waveSums[t & 1][wave] = incl;
        __syncthreads();

        // Block-level: exclusive offset for this wave + tile total.
        float waveOff = 0.0f, tileTot = 0.0f;
        #pragma unroll
        for (int w = 0; w < NWAVES; ++w) {
            const float s = waveSums[t & 1][w];
            if (w < wave) waveOff += s;
            tileTot += s;
        }

        const float base = carry + waveOff + waveExcl;
        float4 r;
        r.x = base + s0;
        r.y = base + s1;
        r.z = base + s2;
        r.w = base + s3;
        o4[t * BLOCK + tid] = r;

        carry += tileTot;
        // No second barrier needed: waveSums is parity double-buffered, and
        // the barrier in iteration t+1 orders reads(t) before writes(t+2).
    }
}

extern "C" void kernel_launch(void* const* d_in, const int* in_sizes, int n_in,
                              void* d_out, int out_size, void* d_ws, size_t ws_size,
                              hipStream_t stream) {
    const float* x    = (const float*)d_in[0];
    const int*   mask = (const int*)d_in[1];
    float*       out  = (float*)d_out;
    (void)in_sizes; (void)n_in; (void)out_size; (void)d_ws; (void)ws_size;

    masked_cumsum_kernel<<<N_ROWS, BLOCK, 0, stream>>>(x, mask, out);
}